// Round 1
// baseline (30.858 us; speedup 1.0000x reference)
//
#include <hip/hip_runtime.h>

constexpr int NUM_SKILLS = 300;
constexpr int EMB = 256;
constexpr int CD  = 64;
constexpr int D3  = 21;   // CURVE_DIM // 3
constexpr int DM  = 22;   // D3 + CURVE_DIM % 3
constexpr int SEQ = 200;

__global__ __launch_bounds__(256)
void traj_enc_kernel(const int* __restrict__ q, const int* __restrict__ r,
                     const float* __restrict__ skill_w, const float* __restrict__ skill_b,
                     const float* __restrict__ att_w,   const float* __restrict__ att_b,
                     const float* __restrict__ mast_w,  const float* __restrict__ mast_b,
                     const float* __restrict__ proj_w,  const float* __restrict__ proj_b,
                     float* __restrict__ out)
{
    __shared__ __align__(16) float sA[EMB];
    __shared__ __align__(16) float sB[EMB];
    __shared__ __align__(16) float sC[EMB];
    __shared__ __align__(16) float sD[EMB];
    __shared__ float s_skill[SEQ], s_att[SEQ], s_mast[SEQ], s_valid[SEQ];
    __shared__ int   s_q[SEQ], s_r[SEQ];

    const int tid = threadIdx.x;
    const int b   = blockIdx.x;

    // stage this batch's q/r rows
    if (tid < SEQ) {
        s_q[tid] = q[b * SEQ + tid];
        s_r[tid] = r[b * SEQ + tid];
    }

    // Phase 0: fold the three scalar encoders + biases into per-e coefficients.
    // traj[e] = skill*A[e] + attempts*B[e] + mastery*C[e] + D[e]
    {
        const float* pw = proj_w + tid * CD;
        float ca = 0.f, cb = 0.f, cc = 0.f, cd = 0.f;
        #pragma unroll
        for (int i = 0; i < D3; ++i) { float w = pw[i];        ca = fmaf(w, skill_w[i], ca); cd = fmaf(w, skill_b[i], cd); }
        #pragma unroll
        for (int i = 0; i < D3; ++i) { float w = pw[D3 + i];   cb = fmaf(w, att_w[i],  cb);  cd = fmaf(w, att_b[i],  cd); }
        #pragma unroll
        for (int i = 0; i < DM; ++i) { float w = pw[2*D3 + i]; cc = fmaf(w, mast_w[i], cc);  cd = fmaf(w, mast_b[i], cd); }
        sA[tid] = ca; sB[tid] = cb; sC[tid] = cc; sD[tid] = cd + proj_b[tid];
    }
    __syncthreads();

    // Phase 1: running counts. attempts[t] = #{t'<=t : valid(q[t']) && q[t']==q[t]}
    if (tid < SEQ) {
        const int myq = s_q[tid];
        int cnt = 0, cor = 0;
        for (int t = 0; t <= tid; ++t) {
            const int qt = s_q[t];
            const bool m = (qt >= 0) && (qt < NUM_SKILLS) && (qt == myq);
            if (m) { cnt += 1; cor += s_r[t]; }
        }
        const float att = (float)cnt;
        s_skill[tid] = (float)myq;
        s_att[tid]   = att;
        s_mast[tid]  = (float)cor / fmaxf(att, 1.0f);
        s_valid[tid] = (myq >= 0 && myq < NUM_SKILLS) ? 1.0f : 0.0f;
    }
    __syncthreads();

    // Phase 2: each thread owns 4 consecutive emb channels; 4 rows per iter.
    const int e4   = tid & 63;
    const int ssub = tid >> 6;
    const float4 A4 = *reinterpret_cast<const float4*>(&sA[e4 * 4]);
    const float4 B4 = *reinterpret_cast<const float4*>(&sB[e4 * 4]);
    const float4 C4 = *reinterpret_cast<const float4*>(&sC[e4 * 4]);
    const float4 D4 = *reinterpret_cast<const float4*>(&sD[e4 * 4]);

    float4* __restrict__ out4 = reinterpret_cast<float4*>(out) + (size_t)b * SEQ * (EMB / 4);
    #pragma unroll 2
    for (int s0 = 0; s0 < SEQ; s0 += 4) {   // SEQ divisible by 4
        const int s = s0 + ssub;
        const float sk = s_skill[s];
        const float at = s_att[s];
        const float ma = s_mast[s];
        const float v  = s_valid[s];
        float4 o;
        o.x = v * fmaf(sk, A4.x, fmaf(at, B4.x, fmaf(ma, C4.x, D4.x)));
        o.y = v * fmaf(sk, A4.y, fmaf(at, B4.y, fmaf(ma, C4.y, D4.y)));
        o.z = v * fmaf(sk, A4.z, fmaf(at, B4.z, fmaf(ma, C4.z, D4.z)));
        o.w = v * fmaf(sk, A4.w, fmaf(at, B4.w, fmaf(ma, C4.w, D4.w)));
        out4[s * (EMB / 4) + e4] = o;
    }
}

extern "C" void kernel_launch(void* const* d_in, const int* in_sizes, int n_in,
                              void* d_out, int out_size, void* d_ws, size_t ws_size,
                              hipStream_t stream)
{
    const int* q        = (const int*)d_in[0];
    const int* r        = (const int*)d_in[1];
    // d_in[2] = qry (unused by the reference)
    const float* skill_w = (const float*)d_in[3];
    const float* skill_b = (const float*)d_in[4];
    const float* att_w   = (const float*)d_in[5];
    const float* att_b   = (const float*)d_in[6];
    const float* mast_w  = (const float*)d_in[7];
    const float* mast_b  = (const float*)d_in[8];
    const float* proj_w  = (const float*)d_in[9];
    const float* proj_b  = (const float*)d_in[10];
    float* out = (float*)d_out;

    const int B = in_sizes[0] / SEQ;  // 512
    traj_enc_kernel<<<B, 256, 0, stream>>>(q, r, skill_w, skill_b, att_w, att_b,
                                           mast_w, mast_b, proj_w, proj_b, out);
}